// Round 5
// baseline (61.080 us; speedup 1.0000x reference)
//
#include <hip/hip_runtime.h>
#include <math.h>

#define BATCH 8
#define HH 192
#define WW 192
#define BIGF 1e10f
#define NROWBLK (BATCH * HH)   // 1536 row-EDT blocks
#define OH (HH - 10)           // 182
#define OW (WW - 10)           // 182
#define NSSIMBLK (BATCH * OH)  // 1456 ssim blocks
#define NENVBLK (BATCH * WW)   // 1536 envelope blocks

__device__ __forceinline__ float waveReduceAdd(float v) {
    #pragma unroll
    for (int o = 32; o > 0; o >>= 1) v += __shfl_down(v, o, 64);
    return v;
}

// Kernel 1 (fused): blocks [0,NROWBLK) per-row 1D EDT (colminT float2{fg,bg},
// transposed [b][x][r]); blocks [NROWBLK,..) one SSIM output row each -> ssimPart.
// Block 0 also zeroes the done-counter for kernel 2 (stream-ordered before use).
__global__ void prepKernel(const float* __restrict__ pred,
                           const int* __restrict__ tgt,
                           float2* __restrict__ colminT,
                           float* __restrict__ ssimPart,
                           unsigned* __restrict__ counter) {
    __shared__ __align__(16) float smem[5 * WW];
    const int x = threadIdx.x;  // 0..191

    if (blockIdx.x == 0 && x == 0) counter[0] = 0;

    if (blockIdx.x < NROWBLK) {
        // ---- row EDT ----
        const int b = blockIdx.x / HH, r = blockIdx.x % HH;
        float* cf = smem;
        float* cb = smem + WW;
        const int t = tgt[(b * HH + r) * WW + x];
        const bool fg = (t > 0);
        cf[x] = fg ? 0.0f : BIGF;
        cb[x] = fg ? BIGF : 0.0f;
        __syncthreads();

        float a0 = BIGF, a1 = BIGF, a2 = BIGF, a3 = BIGF;
        float c0 = BIGF, c1 = BIGF, c2 = BIGF, c3 = BIGF;
        const float fx = (float)x;
        #pragma unroll 6
        for (int xp = 0; xp < WW; xp += 4) {
            const float4 vf = *(const float4*)&cf[xp];
            const float4 vb = *(const float4*)&cb[xp];
            const float e0 = fx - (float)xp;
            const float e1 = fx - (float)(xp + 1);
            const float e2 = fx - (float)(xp + 2);
            const float e3 = fx - (float)(xp + 3);
            a0 = fminf(a0, fmaf(e0, e0, vf.x)); a1 = fminf(a1, fmaf(e1, e1, vf.y));
            a2 = fminf(a2, fmaf(e2, e2, vf.z)); a3 = fminf(a3, fmaf(e3, e3, vf.w));
            c0 = fminf(c0, fmaf(e0, e0, vb.x)); c1 = fminf(c1, fmaf(e1, e1, vb.y));
            c2 = fminf(c2, fmaf(e2, e2, vb.z)); c3 = fminf(c3, fmaf(e3, e3, vb.w));
        }
        const float dfg = fminf(fminf(a0, a1), fminf(a2, a3));
        const float dbg = fminf(fminf(c0, c1), fminf(c2, c3));
        colminT[((size_t)b * WW + x) * HH + r] = make_float2(dfg, dbg);
    } else {
        // ---- SSIM (separable 11-tap gaussian, valid) ----
        const int blk = blockIdx.x - NROWBLK;
        const int b = blk / OH, yo = blk % OH;

        float g[11];
        {
            float s = 0.0f;
            #pragma unroll
            for (int k = 0; k < 11; ++k) {
                const float d = (float)(k - 5);
                g[k] = __expf(-d * d / 4.5f);
                s += g[k];
            }
            const float inv = 1.0f / s;
            #pragma unroll
            for (int k = 0; k < 11; ++k) g[k] *= inv;
        }

        float* sp = smem;
        float* st = smem + WW;
        float* spp = smem + 2 * WW;
        float* stt = smem + 3 * WW;
        float* spt = smem + 4 * WW;

        float ap = 0, at = 0, app = 0, att = 0, apt = 0;
        #pragma unroll
        for (int k = 0; k < 11; ++k) {
            const int row = yo + k;
            const float z = pred[(b * HH + row) * WW + x];
            const float p = 1.0f / (1.0f + __expf(-z));
            const float t = (float)tgt[(b * HH + row) * WW + x];
            const float gk = g[k];
            ap += gk * p; at += gk * t;
            app += gk * p * p; att += gk * t * t; apt += gk * p * t;
        }
        sp[x] = ap; st[x] = at; spp[x] = app; stt[x] = att; spt[x] = apt;
        __syncthreads();

        float term = 0.0f;
        if (x < OW) {
            float mx = 0, my = 0, mxx = 0, myy = 0, mxy = 0;
            #pragma unroll
            for (int k = 0; k < 11; ++k) {
                mx += g[k] * sp[x + k];  my += g[k] * st[x + k];
                mxx += g[k] * spp[x + k]; myy += g[k] * stt[x + k];
                mxy += g[k] * spt[x + k];
            }
            const float C1 = 1e-4f, C2 = 9e-4f;
            const float sx = mxx - mx * mx, sy = myy - my * my, sxy = mxy - mx * my;
            const float num = (2.0f * mx * my + C1) * (2.0f * sxy + C2);
            const float den = (mx * mx + my * my + C1) * (sx + sy + C2);
            term = num / den;
        }
        __shared__ float red1[3];
        const float s = waveReduceAdd(term);
        const int wid = x >> 6;
        if ((x & 63) == 0) red1[wid] = s;
        __syncthreads();
        if (x == 0) ssimPart[blk] = red1[0] + red1[1] + red1[2];
    }
}

// Kernel 2: column envelope + fused losses; per-block partials with release
// publication; last finished block performs the final reduction and writes out.
__global__ void envFinalKernel(const float* __restrict__ pred,
                               const int* __restrict__ tgt,
                               const float2* __restrict__ colminT,
                               float* __restrict__ p0,   // bce partials [NENVBLK]
                               float* __restrict__ p1,   // focal partials
                               float* __restrict__ p2,   // boundary partials
                               const float* __restrict__ ssimPart,
                               unsigned* __restrict__ counter,
                               float* __restrict__ out) {
    const int b = blockIdx.x / WW, cx = blockIdx.x % WW;
    const int y = threadIdx.x;  // 0..191

    __shared__ __align__(16) float2 scfb[HH];
    scfb[y] = colminT[((size_t)b * WW + cx) * HH + y];
    __syncthreads();

    float o0 = BIGF, o1 = BIGF, o2 = BIGF, o3 = BIGF;
    float i0 = BIGF, i1 = BIGF, i2 = BIGF, i3 = BIGF;
    const float fy = (float)y;
    #pragma unroll 6
    for (int rp = 0; rp < HH; rp += 4) {
        const float4 v0 = *(const float4*)&scfb[rp];       // {fg_r, bg_r, fg_r+1, bg_r+1}
        const float4 v1 = *(const float4*)&scfb[rp + 2];
        const float e0 = fy - (float)rp;
        const float e1 = fy - (float)(rp + 1);
        const float e2 = fy - (float)(rp + 2);
        const float e3 = fy - (float)(rp + 3);
        o0 = fminf(o0, fmaf(e0, e0, v0.x)); i0 = fminf(i0, fmaf(e0, e0, v0.y));
        o1 = fminf(o1, fmaf(e1, e1, v0.z)); i1 = fminf(i1, fmaf(e1, e1, v0.w));
        o2 = fminf(o2, fmaf(e2, e2, v1.x)); i2 = fminf(i2, fmaf(e2, e2, v1.y));
        o3 = fminf(o3, fmaf(e3, e3, v1.z)); i3 = fminf(i3, fmaf(e3, e3, v1.w));
    }
    const float d2o = fminf(fminf(o0, o1), fminf(o2, o3));
    const float d2i = fminf(fminf(i0, i1), fminf(i2, i3));

    // empty-mask fallback folds into the clamp: min(1e10, maxd2) -> maxd exactly
    const float maxd2 = (float)((HH - 1) * (HH - 1) + (WW - 1) * (WW - 1));
    const float dist_out = sqrtf(fminf(d2o, maxd2));
    const float dist_in  = sqrtf(fminf(d2i, maxd2));

    const int t = tgt[(b * HH + y) * WW + cx];
    const float tf = (float)t;
    const float phi = (t > 0) ? -dist_in : dist_out;

    const float z = pred[(b * HH + y) * WW + cx];
    const float p = 1.0f / (1.0f + __expf(-z));

    // boundary
    const float wgt = __expf(-fabsf(phi) * 0.1f);
    const float bnd = wgt * fabsf(phi * p);

    // bce (log clamped at -100 like torch BCELoss)
    const float logp   = fmaxf(__logf(p), -100.0f);
    const float log1mp = fmaxf(__logf(1.0f - p), -100.0f);
    const float bce = -(tf * logp + (1.0f - tf) * log1mp);

    // focal
    const float pc = fminf(fmaxf(p, 1e-6f), 1.0f - 1e-6f);
    const float pt = pc * tf + (1.0f - pc) * (1.0f - tf);
    const float at = 0.25f * tf + 0.75f * (1.0f - tf);
    const float om = 1.0f - pt;
    const float focal = -at * om * om * __logf(pt);

    __shared__ float red[3][3];
    __shared__ bool isLast;
    const float sb = waveReduceAdd(bce);
    const float sf = waveReduceAdd(focal);
    const float sd = waveReduceAdd(bnd);
    const int wid = y >> 6;
    if ((y & 63) == 0) { red[wid][0] = sb; red[wid][1] = sf; red[wid][2] = sd; }
    __syncthreads();
    if (y == 0) {
        p0[blockIdx.x] = red[0][0] + red[1][0] + red[2][0];
        p1[blockIdx.x] = red[0][1] + red[1][1] + red[2][1];
        p2[blockIdx.x] = red[0][2] + red[1][2] + red[2][2];
        __threadfence();                      // release: publish partials device-wide
        const unsigned old = atomicAdd(counter, 1u);
        isLast = (old == NENVBLK - 1);
    }
    __syncthreads();

    if (isLast) {
        // acquire: agent-scope atomic loads bypass stale per-XCD cache lines
        float s0 = 0, s1 = 0, s2 = 0, s3 = 0;
        for (int i = y; i < NENVBLK; i += WW) {
            s0 += __hip_atomic_load(&p0[i], __ATOMIC_RELAXED, __HIP_MEMORY_SCOPE_AGENT);
            s1 += __hip_atomic_load(&p1[i], __ATOMIC_RELAXED, __HIP_MEMORY_SCOPE_AGENT);
            s2 += __hip_atomic_load(&p2[i], __ATOMIC_RELAXED, __HIP_MEMORY_SCOPE_AGENT);
        }
        for (int i = y; i < NSSIMBLK; i += WW) s3 += ssimPart[i];  // from kernel 1: safe
        s0 = waveReduceAdd(s0); s1 = waveReduceAdd(s1);
        s2 = waveReduceAdd(s2); s3 = waveReduceAdd(s3);
        __shared__ float red2[3][4];
        if ((y & 63) == 0) { red2[wid][0] = s0; red2[wid][1] = s1; red2[wid][2] = s2; red2[wid][3] = s3; }
        __syncthreads();
        if (y == 0) {
            float t0 = 0, t1 = 0, t2 = 0, t3 = 0;
            #pragma unroll
            for (int w = 0; w < 3; ++w) { t0 += red2[w][0]; t1 += red2[w][1]; t2 += red2[w][2]; t3 += red2[w][3]; }
            const float N1 = (float)(BATCH * HH * WW);
            const float N2 = (float)(BATCH * OH * OW);
            out[0] = (t0 + t1 + t2) / N1 + t3 / N2;
        }
    }
}

extern "C" void kernel_launch(void* const* d_in, const int* in_sizes, int n_in,
                              void* d_out, int out_size, void* d_ws, size_t ws_size,
                              hipStream_t stream) {
    const float* pred = (const float*)d_in[0];
    const int* tgt = (const int*)d_in[1];

    unsigned* counter = (unsigned*)d_ws;                            // 4 B (+pad to 64)
    float* p0 = (float*)((char*)d_ws + 64);                         // 1536*4
    float* p1 = p0 + NENVBLK;
    float* p2 = p1 + NENVBLK;
    float* ssimPart = p2 + NENVBLK;                                 // 1456*4
    float2* colminT = (float2*)((char*)d_ws + 65536);               // 8*192*192*8 = 2359296 B

    prepKernel<<<NROWBLK + NSSIMBLK, WW, 0, stream>>>(pred, tgt, colminT, ssimPart, counter);
    envFinalKernel<<<NENVBLK, WW, 0, stream>>>(pred, tgt, colminT, p0, p1, p2,
                                               ssimPart, counter, (float*)d_out);
}

// Round 6
// 31.251 us; speedup vs baseline: 1.9545x; 1.9545x over previous
//
#include <hip/hip_runtime.h>
#include <math.h>

#define BATCH 8
#define HH 192
#define WW 192
#define BIGF 1e10f
#define NROWBLK (BATCH * HH)   // 1536 row-EDT blocks
#define OH (HH - 10)           // 182
#define OW (WW - 10)           // 182
#define NSSIMBLK (BATCH * OH)  // 1456 ssim blocks
#define NENVBLK (BATCH * WW)   // 1536 envelope blocks

__device__ __forceinline__ float waveReduceAdd(float v) {
    #pragma unroll
    for (int o = 32; o > 0; o >>= 1) v += __shfl_down(v, o, 64);
    return v;
}

// Kernel 1 (fused): blocks [0,NROWBLK) per-row 1D EDT; writes transposed records
// colminT4[b][x][r] = {colmin_fg, colmin_bg, pred_logit, target} so kernel 2 never
// touches pred/tgt (kills its uncoalesced column reads).
// Blocks [NROWBLK,..) compute one SSIM output row each -> ssimPart.
__global__ void prepKernel(const float* __restrict__ pred,
                           const int* __restrict__ tgt,
                           float4* __restrict__ colminT4,
                           float* __restrict__ ssimPart) {
    __shared__ __align__(16) float smem[5 * WW];
    const int x = threadIdx.x;  // 0..191

    if (blockIdx.x < NROWBLK) {
        // ---- row EDT ----
        const int b = blockIdx.x / HH, r = blockIdx.x % HH;
        float* cf = smem;
        float* cb = smem + WW;
        const float z = pred[(b * HH + r) * WW + x];   // coalesced row read
        const int t = tgt[(b * HH + r) * WW + x];      // coalesced row read
        const bool fg = (t > 0);
        cf[x] = fg ? 0.0f : BIGF;
        cb[x] = fg ? BIGF : 0.0f;
        __syncthreads();

        float a0 = BIGF, a1 = BIGF, a2 = BIGF, a3 = BIGF;
        float c0 = BIGF, c1 = BIGF, c2 = BIGF, c3 = BIGF;
        const float fx = (float)x;
        #pragma unroll 6
        for (int xp = 0; xp < WW; xp += 4) {
            const float4 vf = *(const float4*)&cf[xp];
            const float4 vb = *(const float4*)&cb[xp];
            const float e0 = fx - (float)xp;
            const float e1 = fx - (float)(xp + 1);
            const float e2 = fx - (float)(xp + 2);
            const float e3 = fx - (float)(xp + 3);
            a0 = fminf(a0, fmaf(e0, e0, vf.x)); a1 = fminf(a1, fmaf(e1, e1, vf.y));
            a2 = fminf(a2, fmaf(e2, e2, vf.z)); a3 = fminf(a3, fmaf(e3, e3, vf.w));
            c0 = fminf(c0, fmaf(e0, e0, vb.x)); c1 = fminf(c1, fmaf(e1, e1, vb.y));
            c2 = fminf(c2, fmaf(e2, e2, vb.z)); c3 = fminf(c3, fmaf(e3, e3, vb.w));
        }
        const float dfg = fminf(fminf(a0, a1), fminf(a2, a3));
        const float dbg = fminf(fminf(c0, c1), fminf(c2, c3));
        colminT4[((size_t)b * WW + x) * HH + r] = make_float4(dfg, dbg, z, (float)t);
    } else {
        // ---- SSIM (separable 11-tap gaussian, valid) ----
        const int blk = blockIdx.x - NROWBLK;
        const int b = blk / OH, yo = blk % OH;

        float g[11];
        {
            float s = 0.0f;
            #pragma unroll
            for (int k = 0; k < 11; ++k) {
                const float d = (float)(k - 5);
                g[k] = __expf(-d * d / 4.5f);
                s += g[k];
            }
            const float inv = 1.0f / s;
            #pragma unroll
            for (int k = 0; k < 11; ++k) g[k] *= inv;
        }

        float* sp = smem;
        float* st = smem + WW;
        float* spp = smem + 2 * WW;
        float* stt = smem + 3 * WW;
        float* spt = smem + 4 * WW;

        float ap = 0, at = 0, app = 0, att = 0, apt = 0;
        #pragma unroll
        for (int k = 0; k < 11; ++k) {
            const int row = yo + k;
            const float z = pred[(b * HH + row) * WW + x];
            const float p = 1.0f / (1.0f + __expf(-z));
            const float t = (float)tgt[(b * HH + row) * WW + x];
            const float gk = g[k];
            ap += gk * p; at += gk * t;
            app += gk * p * p; att += gk * t * t; apt += gk * p * t;
        }
        sp[x] = ap; st[x] = at; spp[x] = app; stt[x] = att; spt[x] = apt;
        __syncthreads();

        float term = 0.0f;
        if (x < OW) {
            float mx = 0, my = 0, mxx = 0, myy = 0, mxy = 0;
            #pragma unroll
            for (int k = 0; k < 11; ++k) {
                mx += g[k] * sp[x + k];  my += g[k] * st[x + k];
                mxx += g[k] * spp[x + k]; myy += g[k] * stt[x + k];
                mxy += g[k] * spt[x + k];
            }
            const float C1 = 1e-4f, C2 = 9e-4f;
            const float sx = mxx - mx * mx, sy = myy - my * my, sxy = mxy - mx * my;
            const float num = (2.0f * mx * my + C1) * (2.0f * sxy + C2);
            const float den = (mx * mx + my * my + C1) * (sx + sy + C2);
            term = num / den;
        }
        __shared__ float red1[3];
        const float s = waveReduceAdd(term);
        const int wid = x >> 6;
        if ((x & 63) == 0) red1[wid] = s;
        __syncthreads();
        if (x == 0) ssimPart[blk] = red1[0] + red1[1] + red1[2];
    }
}

// Kernel 2: one block per (b, column x). One coalesced float4 load per thread;
// envelope from LDS broadcasts; loss math entirely from registers; per-block
// partial sums (plain stores, no atomics/fences).
__global__ void envKernel(const float4* __restrict__ colminT4,
                          float4* __restrict__ envPart) {
    const int b = blockIdx.x / WW, cx = blockIdx.x % WW;
    const int y = threadIdx.x;  // 0..191

    __shared__ __align__(16) float2 scf[HH];
    const float4 v = colminT4[((size_t)b * WW + cx) * HH + y];  // coalesced 16B/lane
    scf[y] = make_float2(v.x, v.y);
    __syncthreads();

    float o0 = BIGF, o1 = BIGF, o2 = BIGF, o3 = BIGF;
    float i0 = BIGF, i1 = BIGF, i2 = BIGF, i3 = BIGF;
    const float fy = (float)y;
    #pragma unroll 6
    for (int rp = 0; rp < HH; rp += 4) {
        const float4 v0 = *(const float4*)&scf[rp];       // {fg_r, bg_r, fg_r+1, bg_r+1}
        const float4 v1 = *(const float4*)&scf[rp + 2];
        const float e0 = fy - (float)rp;
        const float e1 = fy - (float)(rp + 1);
        const float e2 = fy - (float)(rp + 2);
        const float e3 = fy - (float)(rp + 3);
        o0 = fminf(o0, fmaf(e0, e0, v0.x)); i0 = fminf(i0, fmaf(e0, e0, v0.y));
        o1 = fminf(o1, fmaf(e1, e1, v0.z)); i1 = fminf(i1, fmaf(e1, e1, v0.w));
        o2 = fminf(o2, fmaf(e2, e2, v1.x)); i2 = fminf(i2, fmaf(e2, e2, v1.y));
        o3 = fminf(o3, fmaf(e3, e3, v1.z)); i3 = fminf(i3, fmaf(e3, e3, v1.w));
    }
    const float d2o = fminf(fminf(o0, o1), fminf(o2, o3));
    const float d2i = fminf(fminf(i0, i1), fminf(i2, i3));

    // empty-mask fallback folds into the clamp: min(1e10, maxd2) -> maxd exactly
    const float maxd2 = (float)((HH - 1) * (HH - 1) + (WW - 1) * (WW - 1));
    const float dist_out = sqrtf(fminf(d2o, maxd2));
    const float dist_in  = sqrtf(fminf(d2i, maxd2));

    const float tf = v.w;
    const float phi = (tf > 0.5f) ? -dist_in : dist_out;
    const float p = 1.0f / (1.0f + __expf(-v.z));

    // boundary
    const float wgt = __expf(-fabsf(phi) * 0.1f);
    const float bnd = wgt * fabsf(phi * p);

    // bce (log clamped at -100 like torch BCELoss)
    const float logp   = fmaxf(__logf(p), -100.0f);
    const float log1mp = fmaxf(__logf(1.0f - p), -100.0f);
    const float bce = -(tf * logp + (1.0f - tf) * log1mp);

    // focal
    const float pc = fminf(fmaxf(p, 1e-6f), 1.0f - 1e-6f);
    const float pt = pc * tf + (1.0f - pc) * (1.0f - tf);
    const float at = 0.25f * tf + 0.75f * (1.0f - tf);
    const float om = 1.0f - pt;
    const float focal = -at * om * om * __logf(pt);

    __shared__ float red[3][3];
    const float sb = waveReduceAdd(bce);
    const float sf = waveReduceAdd(focal);
    const float sd = waveReduceAdd(bnd);
    const int wid = y >> 6;
    if ((y & 63) == 0) { red[wid][0] = sb; red[wid][1] = sf; red[wid][2] = sd; }
    __syncthreads();
    if (y == 0) {
        envPart[blockIdx.x] = make_float4(red[0][0] + red[1][0] + red[2][0],
                                          red[0][1] + red[1][1] + red[2][1],
                                          red[0][2] + red[1][2] + red[2][2], 0.0f);
    }
}

// Kernel 3: final reduction + combine
__global__ void reduceKernel(const float4* __restrict__ envPart,
                             const float* __restrict__ ssimPart,
                             float* __restrict__ out) {
    const int tid = threadIdx.x;  // 256
    float s0 = 0, s1 = 0, s2 = 0, s3 = 0;
    for (int i = tid; i < NENVBLK; i += 256) {
        const float4 v = envPart[i];
        s0 += v.x; s1 += v.y; s2 += v.z;
    }
    for (int i = tid; i < NSSIMBLK; i += 256) s3 += ssimPart[i];
    s0 = waveReduceAdd(s0); s1 = waveReduceAdd(s1);
    s2 = waveReduceAdd(s2); s3 = waveReduceAdd(s3);
    __shared__ float red[4][4];
    const int wid = tid >> 6;
    if ((tid & 63) == 0) { red[wid][0] = s0; red[wid][1] = s1; red[wid][2] = s2; red[wid][3] = s3; }
    __syncthreads();
    if (tid == 0) {
        float t0 = 0, t1 = 0, t2 = 0, t3 = 0;
        #pragma unroll
        for (int w = 0; w < 4; ++w) { t0 += red[w][0]; t1 += red[w][1]; t2 += red[w][2]; t3 += red[w][3]; }
        const float N1 = (float)(BATCH * HH * WW);
        const float N2 = (float)(BATCH * OH * OW);
        out[0] = (t0 + t1 + t2) / N1 + t3 / N2;
    }
}

extern "C" void kernel_launch(void* const* d_in, const int* in_sizes, int n_in,
                              void* d_out, int out_size, void* d_ws, size_t ws_size,
                              hipStream_t stream) {
    const float* pred = (const float*)d_in[0];
    const int* tgt = (const int*)d_in[1];

    float4* envPart = (float4*)d_ws;                                // 1536*16 = 24576 B
    float* ssimPart = (float*)((char*)d_ws + 24576);                // 1456*4  = 5824 B
    float4* colminT4 = (float4*)((char*)d_ws + 65536);              // 8*192*192*16 = 4718592 B

    prepKernel<<<NROWBLK + NSSIMBLK, WW, 0, stream>>>(pred, tgt, colminT4, ssimPart);
    envKernel<<<NENVBLK, WW, 0, stream>>>(colminT4, envPart);
    reduceKernel<<<1, 256, 0, stream>>>(envPart, ssimPart, (float*)d_out);
}

// Round 7
// 27.583 us; speedup vs baseline: 2.2144x; 1.1330x over previous
//
#include <hip/hip_runtime.h>
#include <math.h>

#define BATCH 8
#define HH 192
#define WW 192
#define BIGF 1e10f
#define NROWBLK (BATCH * HH)   // 1536 row-EDT blocks
#define OH (HH - 10)           // 182
#define OW (WW - 10)           // 182
#define NSSIMBLK (BATCH * OH)  // 1456 ssim blocks
#define NENVBLK (BATCH * WW)   // 1536 envelope blocks

__device__ __forceinline__ float waveReduceAdd(float v) {
    #pragma unroll
    for (int o = 32; o > 0; o >>= 1) v += __shfl_down(v, o, 64);
    return v;
}

// Nearest set bit in a 192-bit mask (3x u64 words) to position x; returns |x - pos|,
// or a huge value if the mask is empty. Integer-exact.
__device__ __forceinline__ int nearestDist(const unsigned long long m0,
                                           const unsigned long long m1,
                                           const unsigned long long m2,
                                           int x) {
    const unsigned long long m[3] = {m0, m1, m2};
    const int wi = x >> 6, b = x & 63;
    int dL = 1 << 29;
    const unsigned long long low = m[wi] << (63 - b);   // bit b -> pos 63, bits >b dropped
    if (low) dL = __clzll(low);                          // = b - highest_set_pos
    else if (wi >= 1 && m[wi - 1]) dL = b + 1 + __clzll(m[wi - 1]);
    else if (wi == 2 && m[0]) dL = b + 65 + __clzll(m[0]);
    int dR = 1 << 29;
    const unsigned long long high = m[wi] >> b;          // bit b -> pos 0
    if (high) dR = __ffsll((long long)high) - 1;
    else if (wi <= 1 && m[wi + 1]) dR = (64 - b) + __ffsll((long long)m[wi + 1]) - 1;
    else if (wi == 0 && m[2]) dR = (128 - b) + __ffsll((long long)m[2]) - 1;
    return min(dL, dR);
}

// Kernel 1 (fused): blocks [0,NROWBLK) per-row 1D EDT via ballot bitmasks; writes
// transposed packed records colminT[b][x][r] = {f32 logit, dfg | dbg<<8 | t<<16}.
// Blocks [NROWBLK,..) compute one SSIM output row each -> ssimPart.
__global__ void prepKernel(const float* __restrict__ pred,
                           const int* __restrict__ tgt,
                           uint2* __restrict__ colminT,
                           float* __restrict__ ssimPart) {
    __shared__ __align__(16) float smem[5 * WW];
    __shared__ unsigned long long lmask[3];
    const int x = threadIdx.x;  // 0..191

    if (blockIdx.x < NROWBLK) {
        // ---- row EDT (bitmask nearest-set-bit) ----
        const int b = blockIdx.x / HH, r = blockIdx.x % HH;
        const float z = pred[(b * HH + r) * WW + x];   // coalesced
        const int t = tgt[(b * HH + r) * WW + x];      // coalesced
        const int fg = (t > 0) ? 1 : 0;
        const unsigned long long bal = __ballot(fg);
        if ((x & 63) == 0) lmask[x >> 6] = bal;
        __syncthreads();
        const unsigned long long f0 = lmask[0], f1 = lmask[1], f2 = lmask[2];
        int dfg = nearestDist(f0, f1, f2, x);
        int dbg = nearestDist(~f0, ~f1, ~f2, x);
        dfg = min(dfg, 255);   // 255 = "no fg in row" sentinel (real d <= 191)
        dbg = min(dbg, 255);
        colminT[((size_t)b * WW + x) * HH + r] =
            make_uint2(__float_as_uint(z), (unsigned)(dfg | (dbg << 8) | (fg << 16)));
    } else {
        // ---- SSIM (separable 11-tap gaussian, valid) ----
        const int blk = blockIdx.x - NROWBLK;
        const int b = blk / OH, yo = blk % OH;

        float g[11];
        {
            float s = 0.0f;
            #pragma unroll
            for (int k = 0; k < 11; ++k) {
                const float d = (float)(k - 5);
                g[k] = __expf(-d * d / 4.5f);
                s += g[k];
            }
            const float inv = 1.0f / s;
            #pragma unroll
            for (int k = 0; k < 11; ++k) g[k] *= inv;
        }

        float* sp = smem;
        float* st = smem + WW;
        float* spp = smem + 2 * WW;
        float* stt = smem + 3 * WW;
        float* spt = smem + 4 * WW;

        float ap = 0, at = 0, app = 0, att = 0, apt = 0;
        #pragma unroll
        for (int k = 0; k < 11; ++k) {
            const int row = yo + k;
            const float z = pred[(b * HH + row) * WW + x];
            const float p = 1.0f / (1.0f + __expf(-z));
            const float t = (float)tgt[(b * HH + row) * WW + x];
            const float gk = g[k];
            ap += gk * p; at += gk * t;
            app += gk * p * p; att += gk * t * t; apt += gk * p * t;
        }
        sp[x] = ap; st[x] = at; spp[x] = app; stt[x] = att; spt[x] = apt;
        __syncthreads();

        float term = 0.0f;
        if (x < OW) {
            float mx = 0, my = 0, mxx = 0, myy = 0, mxy = 0;
            #pragma unroll
            for (int k = 0; k < 11; ++k) {
                mx += g[k] * sp[x + k];  my += g[k] * st[x + k];
                mxx += g[k] * spp[x + k]; myy += g[k] * stt[x + k];
                mxy += g[k] * spt[x + k];
            }
            const float C1 = 1e-4f, C2 = 9e-4f;
            const float sx = mxx - mx * mx, sy = myy - my * my, sxy = mxy - mx * my;
            const float num = (2.0f * mx * my + C1) * (2.0f * sxy + C2);
            const float den = (mx * mx + my * my + C1) * (sx + sy + C2);
            term = num / den;
        }
        __shared__ float red1[3];
        const float s = waveReduceAdd(term);
        const int wid = x >> 6;
        if ((x & 63) == 0) red1[wid] = s;
        __syncthreads();
        if (x == 0) ssimPart[blk] = red1[0] + red1[1] + red1[2];
    }
}

// Kernel 2: one block per (b, column x). One coalesced 8B load per thread;
// envelope from LDS broadcasts; losses from registers; per-block partials.
__global__ void envKernel(const uint2* __restrict__ colminT,
                          float4* __restrict__ envPart) {
    const int b = blockIdx.x / WW, cx = blockIdx.x % WW;
    const int y = threadIdx.x;  // 0..191

    __shared__ __align__(16) float2 scf[HH];
    const uint2 v = colminT[((size_t)b * WW + cx) * HH + y];  // coalesced 8B/lane
    const int dfg = v.y & 255, dbg = (v.y >> 8) & 255;
    scf[y] = make_float2(dfg == 255 ? BIGF : (float)(dfg * dfg),
                         dbg == 255 ? BIGF : (float)(dbg * dbg));
    __syncthreads();

    float o0 = BIGF, o1 = BIGF, o2 = BIGF, o3 = BIGF;
    float i0 = BIGF, i1 = BIGF, i2 = BIGF, i3 = BIGF;
    const float fy = (float)y;
    #pragma unroll 6
    for (int rp = 0; rp < HH; rp += 4) {
        const float4 v0 = *(const float4*)&scf[rp];       // {fg_r, bg_r, fg_r+1, bg_r+1}
        const float4 v1 = *(const float4*)&scf[rp + 2];
        const float e0 = fy - (float)rp;
        const float e1 = fy - (float)(rp + 1);
        const float e2 = fy - (float)(rp + 2);
        const float e3 = fy - (float)(rp + 3);
        o0 = fminf(o0, fmaf(e0, e0, v0.x)); i0 = fminf(i0, fmaf(e0, e0, v0.y));
        o1 = fminf(o1, fmaf(e1, e1, v0.z)); i1 = fminf(i1, fmaf(e1, e1, v0.w));
        o2 = fminf(o2, fmaf(e2, e2, v1.x)); i2 = fminf(i2, fmaf(e2, e2, v1.y));
        o3 = fminf(o3, fmaf(e3, e3, v1.z)); i3 = fminf(i3, fmaf(e3, e3, v1.w));
    }
    const float d2o = fminf(fminf(o0, o1), fminf(o2, o3));
    const float d2i = fminf(fminf(i0, i1), fminf(i2, i3));

    // empty-mask fallback folds into the clamp: min(1e10, maxd2) -> maxd exactly
    const float maxd2 = (float)((HH - 1) * (HH - 1) + (WW - 1) * (WW - 1));
    const float dist_out = sqrtf(fminf(d2o, maxd2));
    const float dist_in  = sqrtf(fminf(d2i, maxd2));

    const float tf = (float)((v.y >> 16) & 255);
    const float phi = (tf > 0.5f) ? -dist_in : dist_out;
    const float z = __uint_as_float(v.x);
    const float p = 1.0f / (1.0f + __expf(-z));

    // boundary
    const float wgt = __expf(-fabsf(phi) * 0.1f);
    const float bnd = wgt * fabsf(phi * p);

    // bce (log clamped at -100 like torch BCELoss)
    const float logp   = fmaxf(__logf(p), -100.0f);
    const float log1mp = fmaxf(__logf(1.0f - p), -100.0f);
    const float bce = -(tf * logp + (1.0f - tf) * log1mp);

    // focal
    const float pc = fminf(fmaxf(p, 1e-6f), 1.0f - 1e-6f);
    const float pt = pc * tf + (1.0f - pc) * (1.0f - tf);
    const float at = 0.25f * tf + 0.75f * (1.0f - tf);
    const float om = 1.0f - pt;
    const float focal = -at * om * om * __logf(pt);

    __shared__ float red[3][3];
    const float sb = waveReduceAdd(bce);
    const float sf = waveReduceAdd(focal);
    const float sd = waveReduceAdd(bnd);
    const int wid = y >> 6;
    if ((y & 63) == 0) { red[wid][0] = sb; red[wid][1] = sf; red[wid][2] = sd; }
    __syncthreads();
    if (y == 0) {
        envPart[blockIdx.x] = make_float4(red[0][0] + red[1][0] + red[2][0],
                                          red[0][1] + red[1][1] + red[2][1],
                                          red[0][2] + red[1][2] + red[2][2], 0.0f);
    }
}

// Kernel 3: final reduction + combine (1024 threads -> 2 strided iterations)
__global__ void reduceKernel(const float4* __restrict__ envPart,
                             const float* __restrict__ ssimPart,
                             float* __restrict__ out) {
    const int tid = threadIdx.x;  // 0..1023
    float s0 = 0, s1 = 0, s2 = 0, s3 = 0;
    for (int i = tid; i < NENVBLK; i += 1024) {
        const float4 v = envPart[i];
        s0 += v.x; s1 += v.y; s2 += v.z;
    }
    for (int i = tid; i < NSSIMBLK; i += 1024) s3 += ssimPart[i];
    s0 = waveReduceAdd(s0); s1 = waveReduceAdd(s1);
    s2 = waveReduceAdd(s2); s3 = waveReduceAdd(s3);
    __shared__ float red[16][4];
    const int wid = tid >> 6;
    if ((tid & 63) == 0) { red[wid][0] = s0; red[wid][1] = s1; red[wid][2] = s2; red[wid][3] = s3; }
    __syncthreads();
    if (tid == 0) {
        float t0 = 0, t1 = 0, t2 = 0, t3 = 0;
        #pragma unroll
        for (int w = 0; w < 16; ++w) { t0 += red[w][0]; t1 += red[w][1]; t2 += red[w][2]; t3 += red[w][3]; }
        const float N1 = (float)(BATCH * HH * WW);
        const float N2 = (float)(BATCH * OH * OW);
        out[0] = (t0 + t1 + t2) / N1 + t3 / N2;
    }
}

extern "C" void kernel_launch(void* const* d_in, const int* in_sizes, int n_in,
                              void* d_out, int out_size, void* d_ws, size_t ws_size,
                              hipStream_t stream) {
    const float* pred = (const float*)d_in[0];
    const int* tgt = (const int*)d_in[1];

    float4* envPart = (float4*)d_ws;                                // 1536*16 = 24576 B
    float* ssimPart = (float*)((char*)d_ws + 24576);                // 1456*4  = 5824 B
    uint2* colminT = (uint2*)((char*)d_ws + 65536);                 // 8*192*192*8 = 2359296 B

    prepKernel<<<NROWBLK + NSSIMBLK, WW, 0, stream>>>(pred, tgt, colminT, ssimPart);
    envKernel<<<NENVBLK, WW, 0, stream>>>(colminT, envPart);
    reduceKernel<<<1, 1024, 0, stream>>>(envPart, ssimPart, (float*)d_out);
}